// Round 13
// baseline (482.187 us; speedup 1.0000x reference)
//
#include <hip/hip_runtime.h>
#include <stdint.h>

#define DEVINL __device__ __forceinline__

typedef __attribute__((ext_vector_type(8))) __bf16 bf16x8;
typedef __attribute__((ext_vector_type(4))) float f32x4;
typedef __attribute__((ext_vector_type(16))) float f32x16;

static constexpr int HID  = 2048;
static constexpr int NQ   = 6144;   // 3*HID
static constexpr int SEQ  = 2048;
static constexpr int NB   = 4;
static constexpr int MTOT = NB * SEQ;  // 8192

// round-to-nearest-even f32 -> bf16
DEVINL unsigned short f2bf(float f) {
  union { float f; uint32_t u; } x; x.f = f;
  uint32_t r = x.u + 0x7fffu + ((x.u >> 16) & 1u);
  return (unsigned short)(r >> 16);
}

// raw v_exp_f32: 2^x (flushes to 0 below ~-126, fine for softmax tails)
DEVINL float fexp2(float x) { float r; asm("v_exp_f32 %0, %1" : "=v"(r) : "v"(x)); return r; }

typedef const __attribute__((address_space(1))) void gvoid_t;
typedef __attribute__((address_space(3))) void svoid_t;

// async global->LDS, 16B per lane; LDS dest = wave-uniform base + lane*16
DEVINL void gload_lds16(const void* g, void* s) {
  __builtin_amdgcn_global_load_lds((gvoid_t*)(uintptr_t)g,
                                   (svoid_t*)(uint32_t)(uintptr_t)s,
                                   16, 0, 0);
}

// ---------------- merged prep kernel ----------------
// blocks [0, 16384): X f32 -> bf16 (elementwise, float4/lane)
// blocks [16384, 16384+12288): transpose+cvt Wqkv (2048 x 6144)
// blocks [16384+12288, 16384+12288+4096): transpose+cvt Wo (2048 x 2048)
__global__ __launch_bounds__(256) void k_prep(const float* __restrict__ X,
                                              const float* __restrict__ Wqkv,
                                              const float* __restrict__ Wo,
                                              unsigned short* __restrict__ Xbf,
                                              unsigned short* __restrict__ WqkvT,
                                              unsigned short* __restrict__ WoT) {
  __shared__ float tile[32][33];
  const int bid = blockIdx.x;
  if (bid < 16384) {
    const int i = bid * 256 + threadIdx.x;      // n4 = 4194304 exactly = 16384*256
    float4 v = ((const float4*)X)[i];
    ushort4 o;
    o.x = f2bf(v.x); o.y = f2bf(v.y); o.z = f2bf(v.z); o.w = f2bf(v.w);
    ((ushort4*)Xbf)[i] = o;
    return;
  }
  const float* in; unsigned short* out; int R, C, bx, by;
  if (bid < 16384 + 12288) {
    const int r = bid - 16384;
    in = Wqkv; out = WqkvT; R = HID; C = NQ;
    bx = r % (NQ / 32); by = r / (NQ / 32);
  } else {
    const int r = bid - 16384 - 12288;
    in = Wo; out = WoT; R = HID; C = HID;
    bx = r % (HID / 32); by = r / (HID / 32);
  }
  const int c0 = bx * 32, r0 = by * 32;
  const int tx = threadIdx.x & 31, ty = threadIdx.x >> 5;  // 32 x 8
  #pragma unroll
  for (int i = 0; i < 32; i += 8)
    tile[ty + i][tx] = in[(size_t)(r0 + ty + i) * C + (c0 + tx)];
  __syncthreads();
  #pragma unroll
  for (int i = 0; i < 32; i += 8)
    out[(size_t)(c0 + ty + i) * R + (r0 + tx)] = f2bf(tile[tx][ty + i]);
}

// ============ GEMM v3: 256x256 tile, 8 waves, SAME 2-barrier schedule =========
// Round-12 theory: the 49% MfmaUtil ceiling of the 256x128 tile is LDS B-read
// duplication (all 4 waves read the same 128 B-rows -> 4x). 256x256 with 8
// waves (wm 4 x wn 2) keeps per-wave code/resources IDENTICAL (64x128 output,
// acc[4][8], 24 ds_reads + 8 gloads per K-step) but halves B duplication:
// 0.50 KB LDS per MFMA vs 0.56, and 33% fewer HBM bytes per output element.
// LDS 64 KB -> 2 blocks/CU. launch_bounds(512,2) -> VGPR cap 128 >= natural
// ~108 (round-11 lesson: 2nd arg is min BLOCKS/CU; never cap below ~128).
// XOR swizzle slot^=(row&7) source-side (rule 21) + on ds_read (proven).
// Grid 2-D natural (gridDim.x % 8 == 0): XCD = bn % 8, B-panel L2-resident.
// QSCALE: per-16-col frag — Q iff (col % 384) < 128 (a 256-col panel spans
// Q and K regions; each 16-wide frag lies in exactly one region).

template <int OUT_BF16, int QSCALE>
__global__ __launch_bounds__(512, 2) void k_gemm3(const unsigned short* __restrict__ A,
                                                  const unsigned short* __restrict__ BT,
                                                  void* __restrict__ Cout,
                                                  int M, int N, int K) {
  __shared__ unsigned short As[256 * 64];   // A tile rows, swizzled slots
  __shared__ unsigned short Bs[256 * 64];   // BT tile rows, swizzled slots
  const int tid = threadIdx.x;
  const int w = tid >> 6, l = tid & 63;     // w: 0..7
  const int lane16 = l & 15, lgrp = l >> 4;
  const int bn = blockIdx.x, bm = blockIdx.y;
  const int wm = w >> 1, wn = w & 1;        // 4 x 2 wave grid
  const int srow = l >> 3;                  // 0..7 row-within-chunk
  const int gslot = (l & 7) ^ (l >> 3);     // inverse-swizzled global 16B slot

  f32x4 acc[4][8] = {};

  for (int k0 = 0; k0 < K; k0 += 64) {
    // stage A+B: 32 chunks each of 8 rows; wave w does chunks w, w+8, w+16, w+24
    #pragma unroll
    for (int i = 0; i < 4; ++i) {
      const int chunk = i * 8 + w;
      const int row = chunk * 8 + srow;     // 0..255
      gload_lds16(A  + (size_t)(bm * 256 + row) * K + k0 + gslot * 8, As + chunk * 512);
      gload_lds16(BT + (size_t)(bn * 256 + row) * K + k0 + gslot * 8, Bs + chunk * 512);
    }
    __syncthreads();

    #pragma unroll
    for (int kk = 0; kk < 2; ++kk) {
      bf16x8 af[4], bfr[8];
      #pragma unroll
      for (int mf = 0; mf < 4; ++mf) {
        const int row = wm * 64 + mf * 16 + lane16;
        af[mf] = *(const bf16x8*)(As + row * 64 + (((kk * 4 + lgrp) ^ (row & 7)) * 8));
      }
      #pragma unroll
      for (int nf = 0; nf < 8; ++nf) {
        const int row = wn * 128 + nf * 16 + lane16;
        bfr[nf] = *(const bf16x8*)(Bs + row * 64 + (((kk * 4 + lgrp) ^ (row & 7)) * 8));
      }
      #pragma unroll
      for (int mf = 0; mf < 4; ++mf)
        #pragma unroll
        for (int nf = 0; nf < 8; ++nf)
          acc[mf][nf] = __builtin_amdgcn_mfma_f32_16x16x32_bf16(af[mf], bfr[nf], acc[mf][nf], 0, 0, 0);
    }
    __syncthreads();
  }

  // epilogue: wave (wm,wn) owns rows bm*256+wm*64.. , cols bn*256+wn*128..
  const size_t row0 = (size_t)bm * 256 + wm * 64;
  const int col0 = bn * 256 + wn * 128;
  #pragma unroll
  for (int mf = 0; mf < 4; ++mf) {
    #pragma unroll
    for (int nf = 0; nf < 8; ++nf) {
      const int colf = col0 + nf * 16;
      const float qs = (QSCALE && (colf % 384) < 128) ? 0.12751744f : 1.0f;
      const int col = colf + lane16;
      #pragma unroll
      for (int r = 0; r < 4; ++r) {
        const size_t row = row0 + mf * 16 + lgrp * 4 + r;
        if (OUT_BF16)
          ((unsigned short*)Cout)[row * N + col] = f2bf(acc[mf][nf][r] * qs);
        else
          ((float*)Cout)[row * N + col] = acc[mf][nf][r];
      }
    }
  }
}

// ---------------- build V^T per head (coalesced LDS transpose) -------
__global__ __launch_bounds__(256, 2) void k_build_vt2(const unsigned short* __restrict__ QKV,
                                                      unsigned short* __restrict__ Vt) {
  __shared__ unsigned short lt[128][136];   // [tt][d], +8 pad
  const int head = blockIdx.y;              // 0..63
  const int tblk = blockIdx.x;              // 0..15 (128 t each)
  const int b = head >> 4, h = head & 15;
  const int base_row = b * SEQ + h * 128;
  const int tid = threadIdx.x;

  #pragma unroll
  for (int it = 0; it < 8; ++it) {
    const int idx = it * 256 + tid;
    const int tt = idx >> 4, dgrp = idx & 15;
    const uint4 v = *(const uint4*)(QKV + (size_t)(base_row + tblk * 8 + (tt >> 4)) * NQ
                                        + (tt & 15) * 384 + 256 + dgrp * 8);
    *(uint4*)(&lt[tt][dgrp * 8]) = v;
  }
  __syncthreads();

  #pragma unroll
  for (int it = 0; it < 8; ++it) {
    const int idx = it * 256 + tid;
    const int d = idx >> 4, tgrp = idx & 15;
    ushort4 a, bq;
    a.x = lt[tgrp * 8 + 0][d]; a.y = lt[tgrp * 8 + 1][d];
    a.z = lt[tgrp * 8 + 2][d]; a.w = lt[tgrp * 8 + 3][d];
    bq.x = lt[tgrp * 8 + 4][d]; bq.y = lt[tgrp * 8 + 5][d];
    bq.z = lt[tgrp * 8 + 6][d]; bq.w = lt[tgrp * 8 + 7][d];
    unsigned short* dst = Vt + ((size_t)head * 128 + d) * SEQ + tblk * 128 + tgrp * 8;
    *(ushort4*)(dst) = a;
    *(ushort4*)(dst + 4) = bq;
  }
}

// ---------------- flash attention v5 (PROVEN round-12: ~135us) ----
// QBLK=256, 8 waves, grid (8,64)=512 blocks = 2/CU fully resident, zero tail.
// launch_bounds(512,2): VGPR cap 128 >= natural use (round-11 lesson).
// K double-buffered; V single-buffered staged after the post-PV barrier.
__global__ __launch_bounds__(512, 2) void k_attn(const unsigned short* __restrict__ QKV,
                                                 const unsigned short* __restrict__ Vt,
                                                 unsigned short* __restrict__ ATT) {
  __shared__ unsigned short Ks[2][64 * 128];   // [kv][d]  4-bit XOR swizzle, dbuf
  __shared__ unsigned short Vs[128 * 64];      // [d][kv]  3-bit XOR swizzle, single
  const int tid = threadIdx.x, w = tid >> 6, l = tid & 63;   // w: 0..7
  const int l32 = l & 31, hi = l >> 5;
  const int qt = blockIdx.x, head = blockIdx.y;              // qt: 0..7
  const int b = head >> 4, h = head & 15;
  const float THR = 11.5415603f;              // 8 * log2(e): p <= e^8
  const int base_row = b * SEQ + h * 128;

  const int s = qt * 256 + w * 32 + l32;      // global seq position of my q
  bf16x8 qf[8];
  {
    const unsigned short* qrow = QKV + (size_t)(base_row + (s >> 4)) * NQ + (s & 15) * 384;
    #pragma unroll
    for (int dsl = 0; dsl < 8; ++dsl)
      qf[dsl] = *(const bf16x8*)(qrow + dsl * 16 + hi * 8);
  }

  f32x16 oacc[4] = {};   // O^T d-frags: row=d-local (C layout), col=q=l&31
  float mrun = -1e30f, lrun = 0.0f;

  // 16 chunks split over 8 waves (2 each)
  #define STAGE_K(bb, kv0)                                                               \
    {                                                                                    \
      _Pragma("unroll")                                                                  \
      for (int i = 0; i < 2; ++i) {                                                      \
        const int chunk = i * 8 + w;                                                     \
        const int r = chunk * 4 + (l >> 4);                                              \
        const int colsw = ((l & 15) ^ (r & 15)) * 8;                                     \
        gload_lds16(QKV + (size_t)(base_row + ((kv0) >> 4) + (r >> 4)) * NQ              \
                        + (r & 15) * 384 + 128 + colsw,                                  \
                    &Ks[bb][chunk * 512]);                                               \
      }                                                                                  \
    }
  #define STAGE_V(kv0)                                                                   \
    {                                                                                    \
      _Pragma("unroll")                                                                  \
      for (int i = 0; i < 2; ++i) {                                                      \
        const int chunk = i * 8 + w;                                                     \
        const int dr = chunk * 8 + (l >> 3);                                             \
        const int colsw = ((l & 7) ^ (dr & 7)) * 8;                                      \
        gload_lds16(Vt + ((size_t)head * 128 + dr) * SEQ + (kv0) + colsw,                \
                    &Vs[chunk * 512]);                                                   \
      }                                                                                  \
    }

  STAGE_K(0, 0);
  STAGE_V(0);
  __syncthreads();

  int kb = 0;
  for (int kv0 = 0; kv0 < SEQ; kv0 += 64) {
    const int next = kv0 + 64;
    if (next < SEQ) STAGE_K(kb ^ 1, next);   // async; lands during QK+softmax

    // ---- S^T = K * Q^T ----
    f32x16 sacc[2] = {};
    __builtin_amdgcn_s_setprio(1);
    #pragma unroll
    for (int kvf = 0; kvf < 2; ++kvf) {
      const int row = kvf * 32 + l32;
      const unsigned short* kbase = &Ks[kb][row * 128];
      const int rs = (row & 15) << 3;
      #pragma unroll
      for (int dsl = 0; dsl < 8; ++dsl) {
        bf16x8 kf = *(const bf16x8*)(kbase + ((dsl * 16 + hi * 8) ^ rs));
        sacc[kvf] = __builtin_amdgcn_mfma_f32_32x32x16_bf16(kf, qf[dsl], sacc[kvf], 0, 0, 0);
      }
    }
    __builtin_amdgcn_s_setprio(0);

    // ---- online softmax, fully in-register (log2 domain) ----
    float mx[16];
    #pragma unroll
    for (int r = 0; r < 16; ++r) mx[r] = fmaxf(sacc[0][r], sacc[1][r]);
    #pragma unroll
    for (int st = 8; st >= 1; st >>= 1)
      #pragma unroll
      for (int r = 0; r < st; ++r) mx[r] = fmaxf(mx[r], mx[r + st]);
    float pmax = fmaxf(mx[0], __shfl_xor(mx[0], 32));

    if (!__all(pmax - mrun <= THR)) {      // T13 defer-max: rescale rarely
      const float mnew = fmaxf(mrun, pmax);
      const float corr = fexp2(mrun - mnew);
      #pragma unroll
      for (int df = 0; df < 4; ++df)
        #pragma unroll
        for (int r = 0; r < 16; ++r) oacc[df][r] *= corr;
      lrun *= corr;
      mrun = mnew;
    }

    float ps[16];
    #pragma unroll
    for (int r = 0; r < 16; ++r) {
      const float p0 = fexp2(sacc[0][r] - mrun);
      const float p1 = fexp2(sacc[1][r] - mrun);
      sacc[0][r] = p0; sacc[1][r] = p1;
      ps[r] = p0 + p1;
    }
    #pragma unroll
    for (int st = 8; st >= 1; st >>= 1)
      #pragma unroll
      for (int r = 0; r < st; ++r) ps[r] += ps[r + st];
    lrun += ps[0] + __shfl_xor(ps[0], 32);

    // ---- P^T -> bf16 B-fragments: cvt_pk + permlane32_swap (T12) ----
    bf16x8 pf[4];
    #pragma unroll
    for (int f = 0; f < 2; ++f) {
      unsigned int c0, c1, c2, c3, c4, c5, c6, c7;
      asm("v_cvt_pk_bf16_f32 %0, %1, %2" : "=v"(c0) : "v"(sacc[f][0]),  "v"(sacc[f][1]));
      asm("v_cvt_pk_bf16_f32 %0, %1, %2" : "=v"(c1) : "v"(sacc[f][2]),  "v"(sacc[f][3]));
      asm("v_cvt_pk_bf16_f32 %0, %1, %2" : "=v"(c2) : "v"(sacc[f][4]),  "v"(sacc[f][5]));
      asm("v_cvt_pk_bf16_f32 %0, %1, %2" : "=v"(c3) : "v"(sacc[f][6]),  "v"(sacc[f][7]));
      asm("v_cvt_pk_bf16_f32 %0, %1, %2" : "=v"(c4) : "v"(sacc[f][8]),  "v"(sacc[f][9]));
      asm("v_cvt_pk_bf16_f32 %0, %1, %2" : "=v"(c5) : "v"(sacc[f][10]), "v"(sacc[f][11]));
      asm("v_cvt_pk_bf16_f32 %0, %1, %2" : "=v"(c6) : "v"(sacc[f][12]), "v"(sacc[f][13]));
      asm("v_cvt_pk_bf16_f32 %0, %1, %2" : "=v"(c7) : "v"(sacc[f][14]), "v"(sacc[f][15]));
      asm("v_permlane32_swap_b32 %0, %1" : "+v"(c0), "+v"(c2));
      asm("v_permlane32_swap_b32 %0, %1" : "+v"(c1), "+v"(c3));
      asm("v_permlane32_swap_b32 %0, %1" : "+v"(c4), "+v"(c6));
      asm("v_permlane32_swap_b32 %0, %1" : "+v"(c5), "+v"(c7));
      union { unsigned int u[4]; bf16x8 v; } u0, u1;
      u0.u[0] = c0; u0.u[1] = c1; u0.u[2] = c2; u0.u[3] = c3;
      u1.u[0] = c4; u1.u[1] = c5; u1.u[2] = c6; u1.u[3] = c7;
      pf[2 * f] = u0.v; pf[2 * f + 1] = u1.v;
    }

    __syncthreads();   // barrier_B: V(kv0) stage (prologue / prev iter) visible

    // ---- O^T += V^T * P^T ----
    __builtin_amdgcn_s_setprio(1);
    #pragma unroll
    for (int ks = 0; ks < 4; ++ks) {
      #pragma unroll
      for (int df = 0; df < 4; ++df) {
        const int row = df * 32 + l32;
        bf16x8 vf = *(const bf16x8*)(&Vs[row * 64 + (((ks * 16 + hi * 8) ^ ((row & 7) << 3)))]);
        oacc[df] = __builtin_amdgcn_mfma_f32_32x32x16_bf16(vf, pf[ks], oacc[df], 0, 0, 0);
      }
    }
    __builtin_amdgcn_s_setprio(0);

    __syncthreads();   // barrier_A: all waves done reading Vs
    if (next < SEQ) STAGE_V(next);   // async; lands during next QK+softmax
    kb ^= 1;
  }

  // epilogue: O^T/l -> ATT[b*2048+h*128+(s>>4)][(s&15)*128 + d]
  const float inv = 1.0f / lrun;
  unsigned short* orow = ATT + (size_t)(base_row + (s >> 4)) * HID + (s & 15) * 128;
  #pragma unroll
  for (int df = 0; df < 4; ++df) {
    #pragma unroll
    for (int k = 0; k < 4; ++k) {   // d = df*32 + 8k + 4hi + (0..3)
      ushort4 o;
      o.x = f2bf(oacc[df][4 * k + 0] * inv);
      o.y = f2bf(oacc[df][4 * k + 1] * inv);
      o.z = f2bf(oacc[df][4 * k + 2] * inv);
      o.w = f2bf(oacc[df][4 * k + 3] * inv);
      *(ushort4*)(orow + df * 32 + 8 * k + 4 * hi) = o;
    }
  }
}

// ---------------- launcher ----------------

extern "C" void kernel_launch(void* const* d_in, const int* in_sizes, int n_in,
                              void* d_out, int out_size, void* d_ws, size_t ws_size,
                              hipStream_t stream) {
  const float* X    = (const float*)d_in[0];  // (4,2048,2048)
  const float* Wqkv = (const float*)d_in[1];  // (2048,6144)
  const float* Wo   = (const float*)d_in[2];  // (2048,2048)
  float* OUT = (float*)d_out;

  char* ws = (char*)d_ws;
  constexpr size_t SZ_QKV   = (size_t)MTOT * NQ * 2;    // 100663296
  constexpr size_t SZ_XBF   = (size_t)MTOT * HID * 2;   //  33554432
  constexpr size_t SZ_WQKVT = (size_t)NQ * HID * 2;     //  25165824
  constexpr size_t SZ_WOT   = (size_t)HID * HID * 2;    //   8388608
  constexpr size_t SZ_VT    = (size_t)64 * 128 * SEQ * 2; // 33554432
  unsigned short* QKV   = (unsigned short*)(ws);
  unsigned short* Xbf   = (unsigned short*)(ws + SZ_QKV);
  unsigned short* WqkvT = (unsigned short*)(ws + SZ_QKV + SZ_XBF);
  unsigned short* WoT   = (unsigned short*)(ws + SZ_QKV + SZ_XBF + SZ_WQKVT);
  unsigned short* Vt    = (unsigned short*)(ws + SZ_QKV + SZ_XBF + SZ_WQKVT + SZ_WOT);
  unsigned short* ATT   = (unsigned short*)(ws + SZ_QKV + SZ_XBF + SZ_WQKVT + SZ_WOT + SZ_VT);

  // 1) merged prep: X cvt + both weight transposes
  k_prep<<<16384 + 12288 + 4096, 256, 0, stream>>>(X, Wqkv, Wo, Xbf, WqkvT, WoT);
  // 2) QKV projection: 256x256 tile, grid (24, 32) — 24 % 8 == 0 -> XCD = bn % 8
  k_gemm3<1, 1><<<dim3(NQ / 256, MTOT / 256), 512, 0, stream>>>(Xbf, WqkvT, QKV, MTOT, NQ, HID);
  // 3) gather V^T per head (coalesced LDS-transpose version)
  k_build_vt2<<<dim3(16, 64), 256, 0, stream>>>(QKV, Vt);
  // 4) flash attention: QBLK=256, 8 waves, 512 blocks (2/CU, zero tail)
  k_attn<<<dim3(8, 64), 512, 0, stream>>>(QKV, Vt, ATT);
  // 5) output projection: 256x256 tile, grid (8, 32)
  k_gemm3<0, 0><<<dim3(HID / 256, MTOT / 256), 512, 0, stream>>>(ATT, WoT, OUT, MTOT, HID, HID);
}

// Round 14
// 447.834 us; speedup vs baseline: 1.0767x; 1.0767x over previous
//
#include <hip/hip_runtime.h>
#include <stdint.h>

#define DEVINL __device__ __forceinline__

typedef __attribute__((ext_vector_type(8))) __bf16 bf16x8;
typedef __attribute__((ext_vector_type(4))) float f32x4;
typedef __attribute__((ext_vector_type(16))) float f32x16;

static constexpr int HID  = 2048;
static constexpr int NQ   = 6144;   // 3*HID
static constexpr int SEQ  = 2048;
static constexpr int NB   = 4;
static constexpr int MTOT = NB * SEQ;  // 8192

// round-to-nearest-even f32 -> bf16
DEVINL unsigned short f2bf(float f) {
  union { float f; uint32_t u; } x; x.f = f;
  uint32_t r = x.u + 0x7fffu + ((x.u >> 16) & 1u);
  return (unsigned short)(r >> 16);
}

// raw v_exp_f32: 2^x (flushes to 0 below ~-126, fine for softmax tails)
DEVINL float fexp2(float x) { float r; asm("v_exp_f32 %0, %1" : "=v"(r) : "v"(x)); return r; }

typedef const __attribute__((address_space(1))) void gvoid_t;
typedef __attribute__((address_space(3))) void svoid_t;

// async global->LDS, 16B per lane; LDS dest = wave-uniform base + lane*16
DEVINL void gload_lds16(const void* g, void* s) {
  __builtin_amdgcn_global_load_lds((gvoid_t*)(uintptr_t)g,
                                   (svoid_t*)(uint32_t)(uintptr_t)s,
                                   16, 0, 0);
}

// ---------------- merged prep kernel ----------------
// blocks [0, 16384): X f32 -> bf16 (elementwise, float4/lane)
// blocks [16384, 16384+12288): transpose+cvt Wqkv (2048 x 6144)
// blocks [16384+12288, ...+4096): transpose+cvt Wo (2048 x 2048)
__global__ __launch_bounds__(256) void k_prep(const float* __restrict__ X,
                                              const float* __restrict__ Wqkv,
                                              const float* __restrict__ Wo,
                                              unsigned short* __restrict__ Xbf,
                                              unsigned short* __restrict__ WqkvT,
                                              unsigned short* __restrict__ WoT) {
  __shared__ float tile[32][33];
  const int bid = blockIdx.x;
  if (bid < 16384) {
    const int i = bid * 256 + threadIdx.x;      // n4 = 4194304 exactly = 16384*256
    float4 v = ((const float4*)X)[i];
    ushort4 o;
    o.x = f2bf(v.x); o.y = f2bf(v.y); o.z = f2bf(v.z); o.w = f2bf(v.w);
    ((ushort4*)Xbf)[i] = o;
    return;
  }
  const float* in; unsigned short* out; int R, C, bx, by;
  if (bid < 16384 + 12288) {
    const int r = bid - 16384;
    in = Wqkv; out = WqkvT; R = HID; C = NQ;
    bx = r % (NQ / 32); by = r / (NQ / 32);
  } else {
    const int r = bid - 16384 - 12288;
    in = Wo; out = WoT; R = HID; C = HID;
    bx = r % (HID / 32); by = r / (HID / 32);
  }
  const int c0 = bx * 32, r0 = by * 32;
  const int tx = threadIdx.x & 31, ty = threadIdx.x >> 5;  // 32 x 8
  #pragma unroll
  for (int i = 0; i < 32; i += 8)
    tile[ty + i][tx] = in[(size_t)(r0 + ty + i) * C + (c0 + tx)];
  __syncthreads();
  #pragma unroll
  for (int i = 0; i < 32; i += 8)
    out[(size_t)(c0 + ty + i) * R + (r0 + tx)] = f2bf(tile[tx][ty + i]);
}

// ============ GEMM v2 (PROVEN r6/8/12: 196us/49% QKV, 62us OP): C = A * BT^T ====
// Block tile 256(M) x 128(N), BK=64, 4 waves; each wave owns 64x128 output.
// Both A and B staged async via global_load_lds (r7: direct A->VGPR regressed).
// XOR swizzle slot^=(row&7) source-side (rule 21) + on ds_read. Grid 2-D
// natural (gridDim.x % 8 == 0): XCD = bn % 8, B-panel L2-resident (r4/5).
// r13 lesson: do NOT retile to 256x256/8-wave — fewer independent barrier
// groups per CU kills the implicit cross-block overlap (49% -> 38%).
// QSCALE: Q panels (bn%3==0) pre-scaled by 1/sqrt(128)*log2e for exp2 softmax.

template <int OUT_BF16, int QSCALE>
__global__ __launch_bounds__(256, 2) void k_gemm2(const unsigned short* __restrict__ A,
                                                  const unsigned short* __restrict__ BT,
                                                  void* __restrict__ Cout,
                                                  int M, int N, int K) {
  __shared__ unsigned short As[256 * 64];   // A tile rows, swizzled slots
  __shared__ unsigned short Bs[128 * 64];   // BT tile rows, swizzled slots
  const int tid = threadIdx.x;
  const int w = tid >> 6, l = tid & 63;
  const int lane16 = l & 15, lgrp = l >> 4;
  const int bn = blockIdx.x, bm = blockIdx.y;
  const int srow = l >> 3;                  // 0..7 row-within-chunk
  const int gslot = (l & 7) ^ (l >> 3);     // inverse-swizzled global 16B slot

  f32x4 acc[4][8] = {};

  for (int k0 = 0; k0 < K; k0 += 64) {
    #pragma unroll
    for (int i = 0; i < 8; ++i) {
      const int chunk = i * 4 + w;
      const int row = chunk * 8 + srow;     // 0..255
      gload_lds16(A + (size_t)(bm * 256 + row) * K + k0 + gslot * 8, As + chunk * 512);
    }
    #pragma unroll
    for (int i = 0; i < 4; ++i) {
      const int chunk = i * 4 + w;
      const int row = chunk * 8 + srow;     // 0..127
      gload_lds16(BT + (size_t)(bn * 128 + row) * K + k0 + gslot * 8, Bs + chunk * 512);
    }
    __syncthreads();

    #pragma unroll
    for (int kk = 0; kk < 2; ++kk) {
      bf16x8 af[4], bfr[8];
      #pragma unroll
      for (int mf = 0; mf < 4; ++mf) {
        const int row = w * 64 + mf * 16 + lane16;
        af[mf] = *(const bf16x8*)(As + row * 64 + (((kk * 4 + lgrp) ^ (row & 7)) * 8));
      }
      #pragma unroll
      for (int nf = 0; nf < 8; ++nf) {
        const int row = nf * 16 + lane16;
        bfr[nf] = *(const bf16x8*)(Bs + row * 64 + (((kk * 4 + lgrp) ^ (row & 7)) * 8));
      }
      #pragma unroll
      for (int mf = 0; mf < 4; ++mf)
        #pragma unroll
        for (int nf = 0; nf < 8; ++nf)
          acc[mf][nf] = __builtin_amdgcn_mfma_f32_16x16x32_bf16(af[mf], bfr[nf], acc[mf][nf], 0, 0, 0);
    }
    __syncthreads();
  }

  const float qs = (QSCALE && (bn % 3 == 0)) ? 0.12751744f : 1.0f;
  const size_t row0 = (size_t)bm * 256 + w * 64;
  const int col0 = bn * 128;
  #pragma unroll
  for (int mf = 0; mf < 4; ++mf) {
    #pragma unroll
    for (int nf = 0; nf < 8; ++nf) {
      const int col = col0 + nf * 16 + lane16;
      #pragma unroll
      for (int r = 0; r < 4; ++r) {
        const size_t row = row0 + mf * 16 + lgrp * 4 + r;
        if (OUT_BF16)
          ((unsigned short*)Cout)[row * N + col] = f2bf(acc[mf][nf][r] * qs);
        else
          ((float*)Cout)[row * N + col] = acc[mf][nf][r];
      }
    }
  }
}

// ---------------- build V^T per head (coalesced LDS transpose) -------
__global__ __launch_bounds__(256, 2) void k_build_vt2(const unsigned short* __restrict__ QKV,
                                                      unsigned short* __restrict__ Vt) {
  __shared__ unsigned short lt[128][136];   // [tt][d], +8 pad
  const int head = blockIdx.y;              // 0..63
  const int tblk = blockIdx.x;              // 0..15 (128 t each)
  const int b = head >> 4, h = head & 15;
  const int base_row = b * SEQ + h * 128;
  const int tid = threadIdx.x;

  #pragma unroll
  for (int it = 0; it < 8; ++it) {
    const int idx = it * 256 + tid;
    const int tt = idx >> 4, dgrp = idx & 15;
    const uint4 v = *(const uint4*)(QKV + (size_t)(base_row + tblk * 8 + (tt >> 4)) * NQ
                                        + (tt & 15) * 384 + 256 + dgrp * 8);
    *(uint4*)(&lt[tt][dgrp * 8]) = v;
  }
  __syncthreads();

  #pragma unroll
  for (int it = 0; it < 8; ++it) {
    const int idx = it * 256 + tid;
    const int d = idx >> 4, tgrp = idx & 15;
    ushort4 a, bq;
    a.x = lt[tgrp * 8 + 0][d]; a.y = lt[tgrp * 8 + 1][d];
    a.z = lt[tgrp * 8 + 2][d]; a.w = lt[tgrp * 8 + 3][d];
    bq.x = lt[tgrp * 8 + 4][d]; bq.y = lt[tgrp * 8 + 5][d];
    bq.z = lt[tgrp * 8 + 6][d]; bq.w = lt[tgrp * 8 + 7][d];
    unsigned short* dst = Vt + ((size_t)head * 128 + d) * SEQ + tblk * 128 + tgrp * 8;
    *(ushort4*)(dst) = a;
    *(ushort4*)(dst + 4) = bq;
  }
}

// ---------------- flash attention v6: head-major grid for XCD-local K/V ----
// v5 (r12, ~135us) + grid swap: old grid (qt=8, head=64) put the 8 qt-blocks
// of one head on 8 DIFFERENT XCDs (id = qt + 8*head -> XCD = qt%8), each
// refetching the head's 1MB K/V panel (attn FETCH ~278MB vs ~100 ideal).
// New grid (head=64, qt=8): id = head + 64*qt, 64%8==0 -> XCD = head%8 —
// all qt-blocks of a head share one XCD; K/V panel served from its L2.
// Kernel body unchanged. launch_bounds(512,2): VGPR cap 128 (r11 lesson:
// 2nd arg = min blocks/CU; cap = 2048/(blocks*waves) — keep >= 128).
__global__ __launch_bounds__(512, 2) void k_attn(const unsigned short* __restrict__ QKV,
                                                 const unsigned short* __restrict__ Vt,
                                                 unsigned short* __restrict__ ATT) {
  __shared__ unsigned short Ks[2][64 * 128];   // [kv][d]  4-bit XOR swizzle, dbuf
  __shared__ unsigned short Vs[128 * 64];      // [d][kv]  3-bit XOR swizzle, single
  const int tid = threadIdx.x, w = tid >> 6, l = tid & 63;   // w: 0..7
  const int l32 = l & 31, hi = l >> 5;
  const int head = blockIdx.x, qt = blockIdx.y;              // head-major!
  const int b = head >> 4, h = head & 15;
  const float THR = 11.5415603f;              // 8 * log2(e): p <= e^8
  const int base_row = b * SEQ + h * 128;

  const int s = qt * 256 + w * 32 + l32;      // global seq position of my q
  bf16x8 qf[8];
  {
    const unsigned short* qrow = QKV + (size_t)(base_row + (s >> 4)) * NQ + (s & 15) * 384;
    #pragma unroll
    for (int dsl = 0; dsl < 8; ++dsl)
      qf[dsl] = *(const bf16x8*)(qrow + dsl * 16 + hi * 8);
  }

  f32x16 oacc[4] = {};   // O^T d-frags: row=d-local (C layout), col=q=l&31
  float mrun = -1e30f, lrun = 0.0f;

  // 16 chunks split over 8 waves (2 each)
  #define STAGE_K(bb, kv0)                                                               \
    {                                                                                    \
      _Pragma("unroll")                                                                  \
      for (int i = 0; i < 2; ++i) {                                                      \
        const int chunk = i * 8 + w;                                                     \
        const int r = chunk * 4 + (l >> 4);                                              \
        const int colsw = ((l & 15) ^ (r & 15)) * 8;                                     \
        gload_lds16(QKV + (size_t)(base_row + ((kv0) >> 4) + (r >> 4)) * NQ              \
                        + (r & 15) * 384 + 128 + colsw,                                  \
                    &Ks[bb][chunk * 512]);                                               \
      }                                                                                  \
    }
  #define STAGE_V(kv0)                                                                   \
    {                                                                                    \
      _Pragma("unroll")                                                                  \
      for (int i = 0; i < 2; ++i) {                                                      \
        const int chunk = i * 8 + w;                                                     \
        const int dr = chunk * 8 + (l >> 3);                                             \
        const int colsw = ((l & 7) ^ (dr & 7)) * 8;                                      \
        gload_lds16(Vt + ((size_t)head * 128 + dr) * SEQ + (kv0) + colsw,                \
                    &Vs[chunk * 512]);                                                   \
      }                                                                                  \
    }

  STAGE_K(0, 0);
  STAGE_V(0);
  __syncthreads();

  int kb = 0;
  for (int kv0 = 0; kv0 < SEQ; kv0 += 64) {
    const int next = kv0 + 64;
    if (next < SEQ) STAGE_K(kb ^ 1, next);   // async; lands during QK+softmax

    // ---- S^T = K * Q^T ----
    f32x16 sacc[2] = {};
    __builtin_amdgcn_s_setprio(1);
    #pragma unroll
    for (int kvf = 0; kvf < 2; ++kvf) {
      const int row = kvf * 32 + l32;
      const unsigned short* kbase = &Ks[kb][row * 128];
      const int rs = (row & 15) << 3;
      #pragma unroll
      for (int dsl = 0; dsl < 8; ++dsl) {
        bf16x8 kf = *(const bf16x8*)(kbase + ((dsl * 16 + hi * 8) ^ rs));
        sacc[kvf] = __builtin_amdgcn_mfma_f32_32x32x16_bf16(kf, qf[dsl], sacc[kvf], 0, 0, 0);
      }
    }
    __builtin_amdgcn_s_setprio(0);

    // ---- online softmax, fully in-register (log2 domain) ----
    float mx[16];
    #pragma unroll
    for (int r = 0; r < 16; ++r) mx[r] = fmaxf(sacc[0][r], sacc[1][r]);
    #pragma unroll
    for (int st = 8; st >= 1; st >>= 1)
      #pragma unroll
      for (int r = 0; r < st; ++r) mx[r] = fmaxf(mx[r], mx[r + st]);
    float pmax = fmaxf(mx[0], __shfl_xor(mx[0], 32));

    if (!__all(pmax - mrun <= THR)) {      // T13 defer-max: rescale rarely
      const float mnew = fmaxf(mrun, pmax);
      const float corr = fexp2(mrun - mnew);
      #pragma unroll
      for (int df = 0; df < 4; ++df)
        #pragma unroll
        for (int r = 0; r < 16; ++r) oacc[df][r] *= corr;
      lrun *= corr;
      mrun = mnew;
    }

    float ps[16];
    #pragma unroll
    for (int r = 0; r < 16; ++r) {
      const float p0 = fexp2(sacc[0][r] - mrun);
      const float p1 = fexp2(sacc[1][r] - mrun);
      sacc[0][r] = p0; sacc[1][r] = p1;
      ps[r] = p0 + p1;
    }
    #pragma unroll
    for (int st = 8; st >= 1; st >>= 1)
      #pragma unroll
      for (int r = 0; r < st; ++r) ps[r] += ps[r + st];
    lrun += ps[0] + __shfl_xor(ps[0], 32);

    // ---- P^T -> bf16 B-fragments: cvt_pk + permlane32_swap (T12) ----
    bf16x8 pf[4];
    #pragma unroll
    for (int f = 0; f < 2; ++f) {
      unsigned int c0, c1, c2, c3, c4, c5, c6, c7;
      asm("v_cvt_pk_bf16_f32 %0, %1, %2" : "=v"(c0) : "v"(sacc[f][0]),  "v"(sacc[f][1]));
      asm("v_cvt_pk_bf16_f32 %0, %1, %2" : "=v"(c1) : "v"(sacc[f][2]),  "v"(sacc[f][3]));
      asm("v_cvt_pk_bf16_f32 %0, %1, %2" : "=v"(c2) : "v"(sacc[f][4]),  "v"(sacc[f][5]));
      asm("v_cvt_pk_bf16_f32 %0, %1, %2" : "=v"(c3) : "v"(sacc[f][6]),  "v"(sacc[f][7]));
      asm("v_cvt_pk_bf16_f32 %0, %1, %2" : "=v"(c4) : "v"(sacc[f][8]),  "v"(sacc[f][9]));
      asm("v_cvt_pk_bf16_f32 %0, %1, %2" : "=v"(c5) : "v"(sacc[f][10]), "v"(sacc[f][11]));
      asm("v_cvt_pk_bf16_f32 %0, %1, %2" : "=v"(c6) : "v"(sacc[f][12]), "v"(sacc[f][13]));
      asm("v_cvt_pk_bf16_f32 %0, %1, %2" : "=v"(c7) : "v"(sacc[f][14]), "v"(sacc[f][15]));
      asm("v_permlane32_swap_b32 %0, %1" : "+v"(c0), "+v"(c2));
      asm("v_permlane32_swap_b32 %0, %1" : "+v"(c1), "+v"(c3));
      asm("v_permlane32_swap_b32 %0, %1" : "+v"(c4), "+v"(c6));
      asm("v_permlane32_swap_b32 %0, %1" : "+v"(c5), "+v"(c7));
      union { unsigned int u[4]; bf16x8 v; } u0, u1;
      u0.u[0] = c0; u0.u[1] = c1; u0.u[2] = c2; u0.u[3] = c3;
      u1.u[0] = c4; u1.u[1] = c5; u1.u[2] = c6; u1.u[3] = c7;
      pf[2 * f] = u0.v; pf[2 * f + 1] = u1.v;
    }

    __syncthreads();   // barrier_B: V(kv0) stage (prologue / prev iter) visible

    // ---- O^T += V^T * P^T ----
    __builtin_amdgcn_s_setprio(1);
    #pragma unroll
    for (int ks = 0; ks < 4; ++ks) {
      #pragma unroll
      for (int df = 0; df < 4; ++df) {
        const int row = df * 32 + l32;
        bf16x8 vf = *(const bf16x8*)(&Vs[row * 64 + (((ks * 16 + hi * 8) ^ ((row & 7) << 3)))]);
        oacc[df] = __builtin_amdgcn_mfma_f32_32x32x16_bf16(vf, pf[ks], oacc[df], 0, 0, 0);
      }
    }
    __builtin_amdgcn_s_setprio(0);

    __syncthreads();   // barrier_A: all waves done reading Vs
    if (next < SEQ) STAGE_V(next);   // async; lands during next QK+softmax
    kb ^= 1;
  }

  // epilogue: O^T/l -> ATT[b*2048+h*128+(s>>4)][(s&15)*128 + d]
  const float inv = 1.0f / lrun;
  unsigned short* orow = ATT + (size_t)(base_row + (s >> 4)) * HID + (s & 15) * 128;
  #pragma unroll
  for (int df = 0; df < 4; ++df) {
    #pragma unroll
    for (int k = 0; k < 4; ++k) {   // d = df*32 + 8k + 4hi + (0..3)
      ushort4 o;
      o.x = f2bf(oacc[df][4 * k + 0] * inv);
      o.y = f2bf(oacc[df][4 * k + 1] * inv);
      o.z = f2bf(oacc[df][4 * k + 2] * inv);
      o.w = f2bf(oacc[df][4 * k + 3] * inv);
      *(ushort4*)(orow + df * 32 + 8 * k + 4 * hi) = o;
    }
  }
}

// ---------------- launcher ----------------

extern "C" void kernel_launch(void* const* d_in, const int* in_sizes, int n_in,
                              void* d_out, int out_size, void* d_ws, size_t ws_size,
                              hipStream_t stream) {
  const float* X    = (const float*)d_in[0];  // (4,2048,2048)
  const float* Wqkv = (const float*)d_in[1];  // (2048,6144)
  const float* Wo   = (const float*)d_in[2];  // (2048,2048)
  float* OUT = (float*)d_out;

  char* ws = (char*)d_ws;
  constexpr size_t SZ_QKV   = (size_t)MTOT * NQ * 2;    // 100663296
  constexpr size_t SZ_XBF   = (size_t)MTOT * HID * 2;   //  33554432
  constexpr size_t SZ_WQKVT = (size_t)NQ * HID * 2;     //  25165824
  constexpr size_t SZ_WOT   = (size_t)HID * HID * 2;    //   8388608
  constexpr size_t SZ_VT    = (size_t)64 * 128 * SEQ * 2; // 33554432
  unsigned short* QKV   = (unsigned short*)(ws);
  unsigned short* Xbf   = (unsigned short*)(ws + SZ_QKV);
  unsigned short* WqkvT = (unsigned short*)(ws + SZ_QKV + SZ_XBF);
  unsigned short* WoT   = (unsigned short*)(ws + SZ_QKV + SZ_XBF + SZ_WQKVT);
  unsigned short* Vt    = (unsigned short*)(ws + SZ_QKV + SZ_XBF + SZ_WQKVT + SZ_WOT);
  unsigned short* ATT   = (unsigned short*)(ws + SZ_QKV + SZ_XBF + SZ_WQKVT + SZ_WOT + SZ_VT);

  // 1) merged prep: X cvt + both weight transposes
  k_prep<<<16384 + 12288 + 4096, 256, 0, stream>>>(X, Wqkv, Wo, Xbf, WqkvT, WoT);
  // 2) QKV projection: proven 256x128 kernel, grid (48, 32) -> XCD = bn % 8
  k_gemm2<1, 1><<<dim3(NQ / 128, MTOT / 256), 256, 0, stream>>>(Xbf, WqkvT, QKV, MTOT, NQ, HID);
  // 3) gather V^T per head (coalesced LDS-transpose version)
  k_build_vt2<<<dim3(16, 64), 256, 0, stream>>>(QKV, Vt);
  // 4) flash attention: head-major grid (64, 8) -> all qt of a head on one XCD
  k_attn<<<dim3(64, 8), 512, 0, stream>>>(QKV, Vt, ATT);
  // 5) output projection: grid (16, 32)
  k_gemm2<0, 0><<<dim3(HID / 128, MTOT / 256), 256, 0, stream>>>(ATT, WoT, OUT, MTOT, HID, HID);
}